// Round 4
// baseline (180.657 us; speedup 1.0000x reference)
//
#include <hip/hip_runtime.h>
#include <hip/hip_bf16.h>

#define TPB 256
#define ROWS 2
#define BATCH 262144

__device__ __forceinline__ float fast_tanh(float x) {
    float ax = fabsf(x);
    float e  = __expf(-2.0f * ax);
    float t  = (1.0f - e) / (1.0f + e);
    return copysignf(t, x);
}

// RY on wire with bitmask MASK (wire w -> mask 8>>w)
template <int MASK>
__device__ __forceinline__ void ry_gate(float* psi, float c, float s) {
#pragma unroll
    for (int i = 0; i < 16; i++) {
        if (!(i & MASK)) {
            float a = psi[i], b = psi[i | MASK];
            psi[i]        = c * a - s * b;
            psi[i | MASK] = s * a + c * b;
        }
    }
}

// CNOT: when ctrl bit set, swap target bit 0<->1
template <int CM, int TM>
__device__ __forceinline__ void cnot_gate(float* psi) {
#pragma unroll
    for (int i = 0; i < 16; i++) {
        if ((i & CM) && !(i & TM)) {
            float t = psi[i];
            psi[i] = psi[i | TM];
            psi[i | TM] = t;
        }
    }
}

__global__ __launch_bounds__(TPB) void qnet_kernel(
    const float* __restrict__ state,
    const float* __restrict__ W1, const float* __restrict__ b1,
    const float* __restrict__ W2, const float* __restrict__ b2,
    const float* __restrict__ qp,
    const float* __restrict__ H1, const float* __restrict__ c1,
    const float* __restrict__ H2, const float* __restrict__ c2,
    float* __restrict__ out)
{
    __shared__ float sW1[2048];
    __shared__ float sb1[32];
    __shared__ float sW2[128];
    __shared__ float sb2[4];
    __shared__ float sH1[128];
    __shared__ float sc1[32];
    __shared__ float sH2[512];
    __shared__ float sc2[16];
    __shared__ float sQc[8], sQs[8];

    const int tid = threadIdx.x;
    for (int i = tid; i < 2048; i += TPB) sW1[i] = W1[i];
    for (int i = tid; i < 512;  i += TPB) sH2[i] = H2[i];
    if (tid < 128) { sW2[tid] = W2[tid]; sH1[tid] = H1[tid]; }
    if (tid < 32)  { sb1[tid] = b1[tid]; sc1[tid] = c1[tid]; }
    if (tid < 16)  { sc2[tid] = c2[tid]; }
    if (tid < 4)   { sb2[tid] = b2[tid]; }
    if (tid < 8) {
        float s, c;
        __sincosf(0.5f * qp[tid], &s, &c);
        sQs[tid] = s; sQc[tid] = c;
    }
    __syncthreads();

    const int base = blockIdx.x * (TPB * ROWS);
    int bidx[ROWS];
    bidx[0] = base + tid;
    bidx[1] = base + TPB + tid;

    // ---------------- Layer 1: h = relu(x @ W1^T + b1) ----------------
    float h[ROWS][32];
#pragma unroll
    for (int r = 0; r < ROWS; r++)
#pragma unroll
        for (int j = 0; j < 32; j++) h[r][j] = sb1[j];

    const float4* x4[ROWS];
#pragma unroll
    for (int r = 0; r < ROWS; r++)
        x4[r] = reinterpret_cast<const float4*>(state + (size_t)bidx[r] * 64);

#pragma unroll
    for (int ic = 0; ic < 4; ic++) {           // 4 chunks of 16 inputs
        float4 xr[ROWS][4];
#pragma unroll
        for (int r = 0; r < ROWS; r++)
#pragma unroll
            for (int k = 0; k < 4; k++) xr[r][k] = x4[r][ic * 4 + k];

#pragma unroll
        for (int j = 0; j < 32; j++) {
            const float4* w4 = reinterpret_cast<const float4*>(sW1 + j * 64 + ic * 16);
#pragma unroll
            for (int k = 0; k < 4; k++) {
                float4 w = w4[k];
#pragma unroll
                for (int r = 0; r < ROWS; r++) {
                    h[r][j] = fmaf(xr[r][k].x, w.x, h[r][j]);
                    h[r][j] = fmaf(xr[r][k].y, w.y, h[r][j]);
                    h[r][j] = fmaf(xr[r][k].z, w.z, h[r][j]);
                    h[r][j] = fmaf(xr[r][k].w, w.w, h[r][j]);
                }
            }
        }
    }
#pragma unroll
    for (int r = 0; r < ROWS; r++)
#pragma unroll
        for (int j = 0; j < 32; j++) h[r][j] = fmaxf(h[r][j], 0.0f);

    // ---------------- encoded = tanh(h @ W2^T + b2) ----------------
    float e[ROWS][4];
#pragma unroll
    for (int w = 0; w < 4; w++) {
        float acc[ROWS];
#pragma unroll
        for (int r = 0; r < ROWS; r++) acc[r] = sb2[w];
        const float4* w4 = reinterpret_cast<const float4*>(sW2 + w * 32);
#pragma unroll
        for (int k = 0; k < 8; k++) {
            float4 wv = w4[k];
#pragma unroll
            for (int r = 0; r < ROWS; r++) {
                acc[r] = fmaf(h[r][k * 4 + 0], wv.x, acc[r]);
                acc[r] = fmaf(h[r][k * 4 + 1], wv.y, acc[r]);
                acc[r] = fmaf(h[r][k * 4 + 2], wv.z, acc[r]);
                acc[r] = fmaf(h[r][k * 4 + 3], wv.w, acc[r]);
            }
        }
#pragma unroll
        for (int r = 0; r < ROWS; r++) e[r][w] = fast_tanh(acc[r]);
    }

    // ---------------- 4-qubit circuit ----------------
    float qf[ROWS][4];
#pragma unroll
    for (int r = 0; r < ROWS; r++) {
        float psi[16];
#pragma unroll
        for (int i = 0; i < 16; i++) psi[i] = 0.0f;
        psi[0] = 1.0f;

        float s, c;
        __sincosf(0.5f * e[r][0], &s, &c); ry_gate<8>(psi, c, s);
        __sincosf(0.5f * e[r][1], &s, &c); ry_gate<4>(psi, c, s);
        __sincosf(0.5f * e[r][2], &s, &c); ry_gate<2>(psi, c, s);
        __sincosf(0.5f * e[r][3], &s, &c); ry_gate<1>(psi, c, s);

#pragma unroll
        for (int layer = 0; layer < 2; layer++) {
            cnot_gate<8, 4>(psi);   // CNOT(0,1)
            cnot_gate<4, 2>(psi);   // CNOT(1,2)
            cnot_gate<2, 1>(psi);   // CNOT(2,3)
            cnot_gate<1, 8>(psi);   // CNOT(3,0)
            ry_gate<8>(psi, sQc[layer * 4 + 0], sQs[layer * 4 + 0]);
            ry_gate<4>(psi, sQc[layer * 4 + 1], sQs[layer * 4 + 1]);
            ry_gate<2>(psi, sQc[layer * 4 + 2], sQs[layer * 4 + 2]);
            ry_gate<1>(psi, sQc[layer * 4 + 3], sQs[layer * 4 + 3]);
        }

        float p[16];
#pragma unroll
        for (int i = 0; i < 16; i++) p[i] = psi[i] * psi[i];
#pragma unroll
        for (int w = 0; w < 4; w++) {
            const int m = 8 >> w;
            float z = 0.0f;
#pragma unroll
            for (int i = 0; i < 16; i++) z += (i & m) ? -p[i] : p[i];
            qf[r][w] = z;
        }
    }

    // ---------------- h2 = relu(qf @ H1^T + c1) ----------------
    float h2[ROWS][32];
#pragma unroll
    for (int j = 0; j < 32; j++) {
        const float4 hv = *reinterpret_cast<const float4*>(sH1 + j * 4);
#pragma unroll
        for (int r = 0; r < ROWS; r++) {
            float a = sc1[j];
            a = fmaf(qf[r][0], hv.x, a);
            a = fmaf(qf[r][1], hv.y, a);
            a = fmaf(qf[r][2], hv.z, a);
            a = fmaf(qf[r][3], hv.w, a);
            h2[r][j] = fmaxf(a, 0.0f);
        }
    }

    // ---------------- q = tanh(h2 @ H2^T + c2), store f32 ----------------
    float qv[ROWS][16];
#pragma unroll
    for (int o = 0; o < 16; o++) {
        const float4* w4 = reinterpret_cast<const float4*>(sH2 + o * 32);
        float acc[ROWS];
#pragma unroll
        for (int r = 0; r < ROWS; r++) acc[r] = sc2[o];
#pragma unroll
        for (int k = 0; k < 8; k++) {
            float4 wv = w4[k];
#pragma unroll
            for (int r = 0; r < ROWS; r++) {
                acc[r] = fmaf(h2[r][k * 4 + 0], wv.x, acc[r]);
                acc[r] = fmaf(h2[r][k * 4 + 1], wv.y, acc[r]);
                acc[r] = fmaf(h2[r][k * 4 + 2], wv.z, acc[r]);
                acc[r] = fmaf(h2[r][k * 4 + 3], wv.w, acc[r]);
            }
        }
#pragma unroll
        for (int r = 0; r < ROWS; r++) qv[r][o] = fast_tanh(acc[r]);
    }

#pragma unroll
    for (int r = 0; r < ROWS; r++) {
        float4* dst = reinterpret_cast<float4*>(out + (size_t)bidx[r] * 16);
#pragma unroll
        for (int k = 0; k < 4; k++) {
            dst[k] = make_float4(qv[r][k * 4 + 0], qv[r][k * 4 + 1],
                                 qv[r][k * 4 + 2], qv[r][k * 4 + 3]);
        }
    }
}

extern "C" void kernel_launch(void* const* d_in, const int* in_sizes, int n_in,
                              void* d_out, int out_size, void* d_ws, size_t ws_size,
                              hipStream_t stream) {
    const float* state = (const float*)d_in[0];
    const float* W1    = (const float*)d_in[1];
    const float* b1    = (const float*)d_in[2];
    const float* W2    = (const float*)d_in[3];
    const float* b2    = (const float*)d_in[4];
    const float* qp    = (const float*)d_in[5];
    const float* H1    = (const float*)d_in[6];
    const float* c1    = (const float*)d_in[7];
    const float* H2    = (const float*)d_in[8];
    const float* c2    = (const float*)d_in[9];
    float* out = (float*)d_out;

    const int blocks = BATCH / (TPB * ROWS);   // 512
    qnet_kernel<<<blocks, TPB, 0, stream>>>(state, W1, b1, W2, b2, qp,
                                            H1, c1, H2, c2, out);
}

// Round 5
// 143.860 us; speedup vs baseline: 1.2558x; 1.2558x over previous
//
#include <hip/hip_runtime.h>
#include <hip/hip_bf16.h>

#define TPB 256
#define BATCH 262144

__device__ __forceinline__ float fast_tanh(float x) {
    float ax = fabsf(x);
    float e  = __expf(-2.0f * ax);
    float t  = (1.0f - e) / (1.0f + e);
    return copysignf(t, x);
}

// RY on wire with bitmask MASK (wire w -> mask 8>>w)
template <int MASK>
__device__ __forceinline__ void ry_gate(float* psi, float c, float s) {
#pragma unroll
    for (int i = 0; i < 16; i++) {
        if (!(i & MASK)) {
            float a = psi[i], b = psi[i | MASK];
            psi[i]        = c * a - s * b;
            psi[i | MASK] = s * a + c * b;
        }
    }
}

// CNOT: when ctrl bit set, swap target bit 0<->1
template <int CM, int TM>
__device__ __forceinline__ void cnot_gate(float* psi) {
#pragma unroll
    for (int i = 0; i < 16; i++) {
        if ((i & CM) && !(i & TM)) {
            float t = psi[i];
            psi[i] = psi[i | TM];
            psi[i | TM] = t;
        }
    }
}

__global__ __launch_bounds__(TPB) void qnet_kernel(
    const float* __restrict__ state,
    const float* __restrict__ W1, const float* __restrict__ b1,
    const float* __restrict__ W2, const float* __restrict__ b2,
    const float* __restrict__ qp,
    const float* __restrict__ H1, const float* __restrict__ c1,
    const float* __restrict__ H2, const float* __restrict__ c2,
    float* __restrict__ out)
{
    __shared__ float sW1[2048];
    __shared__ float sb1[32];
    __shared__ float sW2[128];
    __shared__ float sb2[4];
    __shared__ float sH1[128];
    __shared__ float sc1[32];
    __shared__ float sH2[512];
    __shared__ float sc2[16];
    __shared__ float sQc[8], sQs[8];

    const int tid = threadIdx.x;
    for (int i = tid; i < 2048; i += TPB) sW1[i] = W1[i];
    for (int i = tid; i < 512;  i += TPB) sH2[i] = H2[i];
    if (tid < 128) { sW2[tid] = W2[tid]; sH1[tid] = H1[tid]; }
    if (tid < 32)  { sb1[tid] = b1[tid]; sc1[tid] = c1[tid]; }
    if (tid < 16)  { sc2[tid] = c2[tid]; }
    if (tid < 4)   { sb2[tid] = b2[tid]; }
    if (tid < 8) {
        float s, c;
        __sincosf(0.5f * qp[tid], &s, &c);
        sQs[tid] = s; sQc[tid] = c;
    }
    __syncthreads();

    const int bidx = blockIdx.x * TPB + tid;

    // ---------------- Layer 1: h = relu(x @ W1^T + b1) ----------------
    float h[32];
#pragma unroll
    for (int j = 0; j < 32; j++) h[j] = sb1[j];

    const float4* x4 = reinterpret_cast<const float4*>(state + (size_t)bidx * 64);

#pragma unroll
    for (int ic = 0; ic < 4; ic++) {           // 4 chunks of 16 inputs
        float4 xr[4];
#pragma unroll
        for (int k = 0; k < 4; k++) xr[k] = x4[ic * 4 + k];

#pragma unroll
        for (int j = 0; j < 32; j++) {
            const float4* w4 = reinterpret_cast<const float4*>(sW1 + j * 64 + ic * 16);
#pragma unroll
            for (int k = 0; k < 4; k++) {
                float4 w = w4[k];
                h[j] = fmaf(xr[k].x, w.x, h[j]);
                h[j] = fmaf(xr[k].y, w.y, h[j]);
                h[j] = fmaf(xr[k].z, w.z, h[j]);
                h[j] = fmaf(xr[k].w, w.w, h[j]);
            }
        }
    }
#pragma unroll
    for (int j = 0; j < 32; j++) h[j] = fmaxf(h[j], 0.0f);

    // ---------------- encoded = tanh(h @ W2^T + b2) ----------------
    float e[4];
#pragma unroll
    for (int w = 0; w < 4; w++) {
        float acc = sb2[w];
        const float4* w4 = reinterpret_cast<const float4*>(sW2 + w * 32);
#pragma unroll
        for (int k = 0; k < 8; k++) {
            float4 wv = w4[k];
            acc = fmaf(h[k * 4 + 0], wv.x, acc);
            acc = fmaf(h[k * 4 + 1], wv.y, acc);
            acc = fmaf(h[k * 4 + 2], wv.z, acc);
            acc = fmaf(h[k * 4 + 3], wv.w, acc);
        }
        e[w] = fast_tanh(acc);
    }

    // ---------------- 4-qubit circuit ----------------
    float qf[4];
    {
        float psi[16];
#pragma unroll
        for (int i = 0; i < 16; i++) psi[i] = 0.0f;
        psi[0] = 1.0f;

        float s, c;
        __sincosf(0.5f * e[0], &s, &c); ry_gate<8>(psi, c, s);
        __sincosf(0.5f * e[1], &s, &c); ry_gate<4>(psi, c, s);
        __sincosf(0.5f * e[2], &s, &c); ry_gate<2>(psi, c, s);
        __sincosf(0.5f * e[3], &s, &c); ry_gate<1>(psi, c, s);

#pragma unroll
        for (int layer = 0; layer < 2; layer++) {
            cnot_gate<8, 4>(psi);   // CNOT(0,1)
            cnot_gate<4, 2>(psi);   // CNOT(1,2)
            cnot_gate<2, 1>(psi);   // CNOT(2,3)
            cnot_gate<1, 8>(psi);   // CNOT(3,0)
            ry_gate<8>(psi, sQc[layer * 4 + 0], sQs[layer * 4 + 0]);
            ry_gate<4>(psi, sQc[layer * 4 + 1], sQs[layer * 4 + 1]);
            ry_gate<2>(psi, sQc[layer * 4 + 2], sQs[layer * 4 + 2]);
            ry_gate<1>(psi, sQc[layer * 4 + 3], sQs[layer * 4 + 3]);
        }

        float p[16];
#pragma unroll
        for (int i = 0; i < 16; i++) p[i] = psi[i] * psi[i];
#pragma unroll
        for (int w = 0; w < 4; w++) {
            const int m = 8 >> w;
            float z = 0.0f;
#pragma unroll
            for (int i = 0; i < 16; i++) z += (i & m) ? -p[i] : p[i];
            qf[w] = z;
        }
    }

    // ---------------- h2 = relu(qf @ H1^T + c1) ----------------
    float h2[32];
#pragma unroll
    for (int j = 0; j < 32; j++) {
        const float4 hv = *reinterpret_cast<const float4*>(sH1 + j * 4);
        float a = sc1[j];
        a = fmaf(qf[0], hv.x, a);
        a = fmaf(qf[1], hv.y, a);
        a = fmaf(qf[2], hv.z, a);
        a = fmaf(qf[3], hv.w, a);
        h2[j] = fmaxf(a, 0.0f);
    }

    // ---------------- q = tanh(h2 @ H2^T + c2), store f32 ----------------
    float qv[16];
#pragma unroll
    for (int o = 0; o < 16; o++) {
        const float4* w4 = reinterpret_cast<const float4*>(sH2 + o * 32);
        float acc = sc2[o];
#pragma unroll
        for (int k = 0; k < 8; k++) {
            float4 wv = w4[k];
            acc = fmaf(h2[k * 4 + 0], wv.x, acc);
            acc = fmaf(h2[k * 4 + 1], wv.y, acc);
            acc = fmaf(h2[k * 4 + 2], wv.z, acc);
            acc = fmaf(h2[k * 4 + 3], wv.w, acc);
        }
        qv[o] = fast_tanh(acc);
    }

    float4* dst = reinterpret_cast<float4*>(out + (size_t)bidx * 16);
#pragma unroll
    for (int k = 0; k < 4; k++) {
        dst[k] = make_float4(qv[k * 4 + 0], qv[k * 4 + 1],
                             qv[k * 4 + 2], qv[k * 4 + 3]);
    }
}

extern "C" void kernel_launch(void* const* d_in, const int* in_sizes, int n_in,
                              void* d_out, int out_size, void* d_ws, size_t ws_size,
                              hipStream_t stream) {
    const float* state = (const float*)d_in[0];
    const float* W1    = (const float*)d_in[1];
    const float* b1    = (const float*)d_in[2];
    const float* W2    = (const float*)d_in[3];
    const float* b2    = (const float*)d_in[4];
    const float* qp    = (const float*)d_in[5];
    const float* H1    = (const float*)d_in[6];
    const float* c1    = (const float*)d_in[7];
    const float* H2    = (const float*)d_in[8];
    const float* c2    = (const float*)d_in[9];
    float* out = (float*)d_out;

    const int blocks = BATCH / TPB;   // 1024
    qnet_kernel<<<blocks, TPB, 0, stream>>>(state, W1, b1, W2, b2, qp,
                                            H1, c1, H2, c2, out);
}